// Round 15
// baseline (416.089 us; speedup 1.0000x reference)
//
#include <hip/hip_runtime.h>
#include <stdint.h>

#define VN   1000000
#define VDIM 256
#define GDIM 256
#define NH   16
#define NG   50000
#define HIDD 128
#define NTILES 15625   // VN / 64
#define NZBLK 13282    // zero blocks: ceil((NG*GDIM/4 + NG*NH/4)/256)

using bf16x8 = __attribute__((ext_vector_type(8))) __bf16;
using f32x4  = __attribute__((ext_vector_type(4))) float;

__device__ __forceinline__ unsigned short f2bf(float f) {
  __bf16 h = (__bf16)f;                 // native RNE (v_cvt_pk_bf16_f32)
  return __builtin_bit_cast(unsigned short, h);
}
__device__ __forceinline__ bf16x8 pack8(float4 a, float4 b) {
  bf16x8 r;
  r[0] = (__bf16)a.x; r[1] = (__bf16)a.y; r[2] = (__bf16)a.z; r[3] = (__bf16)a.w;
  r[4] = (__bf16)b.x; r[5] = (__bf16)b.y; r[6] = (__bf16)b.z; r[7] = (__bf16)b.w;
  return r;
}
__device__ __forceinline__ f32x4 fzero4() { f32x4 z = {0.f, 0.f, 0.f, 0.f}; return z; }

// ---------------- init: zero out+denom AND weight prep (merged, one launch) ----------------
__global__ void k_init(const float* __restrict__ s1, const float* __restrict__ s2,
                       const float* __restrict__ t1, const float* __restrict__ t2,
                       unsigned short* __restrict__ WB,
                       float* __restrict__ out, float* __restrict__ denom) {
  if (blockIdx.x < NZBLK) {
    int i = blockIdx.x * 256 + threadIdx.x;
    float4 z = make_float4(0.f, 0.f, 0.f, 0.f);
    if (i < NG * GDIM / 4) ((float4*)out)[i] = z;
    int j = i - NG * GDIM / 4;
    if (j >= 0 && j < NG * NH / 4) ((float4*)denom)[j] = z;
    return;
  }
  int t = (blockIdx.x - NZBLK) * 256 + threadIdx.x;
  const float* W; unsigned short* dst; int K, N, lid;
  if (t < 32768)       { W = s1; dst = WB;          K = 256; N = 128; lid = t; }
  else if (t < 65536)  { W = t1; dst = WB + 32768;  K = 256; N = 128; lid = t - 32768; }
  else if (t < 98304)  { W = t2; dst = WB + 65536;  K = 128; N = 256; lid = t - 65536; }
  else if (t < 100352) { W = s2; dst = WB + 98304;  K = 128; N = 16;  lid = t - 98304; }
  else return;
  int j = lid & 7, l = (lid >> 3) & 63, rem = lid >> 9;
  int KS = K >> 5;
  int s = rem % KS, c = rem / KS;
  int row = 32 * s + 8 * (l >> 4) + j;
  int col = 16 * c + (l & 15);
  dst[lid] = f2bf(W[row * N + col]);
}

// ---------------- fused main: one 64-row tile per block, 512 thr / 8 waves, 3 blocks/CU ----------------
// LDS (36 KB): U[0,32768) = Xs during {A,B}; after bar2 re-used as Hs [0,16384) + Ts [16384,32768)
//              exs f32[64][16] at [32768,36864)
// lb(512,3) -> arch-VGPR cap ~85 -> 3 blocks/CU (24 waves): +50% TLP vs R13's 2 blocks,
// while keeping enough registers for several-ks-deep weight-fragment hoisting (the R12
// cap-64 stall). Nothing held across barriers except MFMA acc.
__global__ __launch_bounds__(512, 3) void k_main(
    const float* __restrict__ X,
    const unsigned short* __restrict__ WBs1,
    const unsigned short* __restrict__ WBt1,
    const unsigned short* __restrict__ WBs2,
    const unsigned short* __restrict__ WBt2,
    const int* __restrict__ seg,
    float* __restrict__ denom,
    float* __restrict__ out) {
  __shared__ __align__(16) char U[36864];
  char* const Xs = U;
  char* const Hs = U;            // aliases Xs after bar2
  char* const Ts = U + 16384;
  float* const exs = (float*)(U + 32768);

  const int tid  = threadIdx.x;
  const int lane = tid & 63;
  const int w    = tid >> 6;     // 0..7
  const int lg   = lane >> 4;
  const int ml   = lane & 15;
  const size_t base = (size_t)blockIdx.x * 64;

  // per-lane graph id for the tile's 64 rows (lane <-> row)
  const int gv = seg[base + lane];
  const int gp = __shfl_up(gv, 1, 64);
  const unsigned long long bmask = __ballot(gv != gp) | 1ull;  // segment-start rows

  // ---- Phase A: stage X -> bf16 LDS. 32B chunks: 2x float4 -> pack8 (cvt_pk) -> one 16B swz write
  {
    const float4* Xg = (const float4*)(X + base * VDIM);
    #pragma unroll
    for (int p = 0; p < 4; ++p) {
      const int c32 = tid + 512 * p;          // 32B fp32 chunk, 2048 total
      const int row = c32 >> 5, c8 = c32 & 31;
      float4 a = Xg[2 * c32], b = Xg[2 * c32 + 1];
      *(bf16x8*)(Xs + row * 512 + ((c8 * 16) ^ ((row & 7) << 4))) = pack8(a, b);
    }
  }
  __syncthreads();   // bar1: Xs ready

  // ---- Phase B: C1[64][256] = relu(X @ [Sw1|Tw1]); waves 0-3 -> Sw1 cf{2w,2w+1}, 4-7 -> Tw1
  const unsigned short* Wb1 = (w < 4) ? WBs1 : WBt1;
  const int cw = 2 * (w & 3);
  {
    f32x4 acc[4][2];
    #pragma unroll
    for (int r = 0; r < 4; ++r) { acc[r][0] = fzero4(); acc[r][1] = fzero4(); }

    #pragma unroll
    for (int ks = 0; ks < 8; ++ks) {
      bf16x8 A[4];
      #pragma unroll
      for (int r = 0; r < 4; ++r) {
        const int row = 16 * r + ml;
        const int cb = 64 * ks + 16 * lg;
        A[r] = *(const bf16x8*)(Xs + row * 512 + (cb ^ ((row & 7) << 4)));
      }
      #pragma unroll
      for (int ci = 0; ci < 2; ++ci) {
        bf16x8 B = *(const bf16x8*)(Wb1 + (size_t)(((cw + ci) * 8 + ks) * 64 + lane) * 8);
        #pragma unroll
        for (int r = 0; r < 4; ++r)
          acc[r][ci] = __builtin_amdgcn_mfma_f32_16x16x32_bf16(A[r], B, acc[r][ci], 0, 0, 0);
      }
    }
    __syncthreads();   // bar2: all Xs reads done; U becomes Hs/Ts

    // relu + bf16 -> Hs (waves 0-3) / Ts (waves 4-7), [64][128] 256B swizzled rows
    char* const dst = (w < 4) ? Hs : Ts;
    #pragma unroll
    for (int ci = 0; ci < 2; ++ci) {
      const int colf = cw + ci;
      #pragma unroll
      for (int r = 0; r < 4; ++r)
        #pragma unroll
        for (int j = 0; j < 4; ++j) {
          const int row = 16 * r + 4 * lg + j;
          const int col = 16 * colf + ml;
          float v = acc[r][ci][j];
          v = v > 0.f ? v : 0.f;
          *(unsigned short*)(dst + row * 256 + ((col * 2) ^ ((row & 7) << 4))) = f2bf(v);
        }
    }
  }
  __syncthreads();   // bar3: Hs/Ts complete

  // ---- Phase C1 (waves 0-3): scores = H1 @ Sw2, rows 16w..16w+15; ex -> exs + denom atomics
  if (w < 4) {
    f32x4 sa = fzero4();
    #pragma unroll
    for (int ks = 0; ks < 4; ++ks) {
      const int row = 16 * w + ml;
      const int cb = 64 * ks + 16 * lg;
      bf16x8 A2 = *(const bf16x8*)(Hs + row * 256 + (cb ^ ((row & 7) << 4)));
      bf16x8 B2 = *(const bf16x8*)(WBs2 + (size_t)(ks * 64 + lane) * 8);
      sa = __builtin_amdgcn_mfma_f32_16x16x32_bf16(A2, B2, sa, 0, 0, 0);
    }
    const int rowbase = 16 * w + 4 * lg;
    float ex[4]; int gs[4];
    #pragma unroll
    for (int j = 0; j < 4; ++j) {
      ex[j] = __expf(sa[j]);                     // |score| ~< 1.5: no max-subtract needed
      gs[j] = __shfl(gv, rowbase + j, 64);
      exs[(rowbase + j) * 16 + ml] = ex[j];
    }
    float accd = ex[0]; int gcur = gs[0];
    #pragma unroll
    for (int j = 1; j < 4; ++j) {
      if (gs[j] == gcur) accd += ex[j];
      else { atomicAdd(denom + (size_t)gcur * NH + ml, accd); gcur = gs[j]; accd = ex[j]; }
    }
    atomicAdd(denom + (size_t)gcur * NH + ml, accd);
  }

  // ---- Phase C2: R = T1 @ Tw2 ; wave w -> col-frags {2w, 2w+1} of 16
  f32x4 racc[4][2];
  #pragma unroll
  for (int r = 0; r < 4; ++r) { racc[r][0] = fzero4(); racc[r][1] = fzero4(); }
  #pragma unroll
  for (int ks = 0; ks < 4; ++ks) {
    bf16x8 A[4];
    #pragma unroll
    for (int r = 0; r < 4; ++r) {
      const int row = 16 * r + ml;
      const int cb = 64 * ks + 16 * lg;
      A[r] = *(const bf16x8*)(Ts + row * 256 + (cb ^ ((row & 7) << 4)));
    }
    #pragma unroll
    for (int ci = 0; ci < 2; ++ci) {
      bf16x8 B = *(const bf16x8*)(WBt2 + (size_t)(((2 * w + ci) * 4 + ks) * 64 + lane) * 8);
      #pragma unroll
      for (int r = 0; r < 4; ++r)
        racc[r][ci] = __builtin_amdgcn_mfma_f32_16x16x32_bf16(A[r], B, racc[r][ci], 0, 0, 0);
    }
  }
  __syncthreads();   // bar4: exs fully written by all C1 waves

  // ---- Phase D: racc = relu(racc) * ex[row][2w+ci]
  #pragma unroll
  for (int r = 0; r < 4; ++r)
    #pragma unroll
    for (int j = 0; j < 4; ++j) {
      const int row = 16 * r + 4 * lg + j;
      const float2 e = *(const float2*)(exs + row * 16 + 2 * w);
      float v0 = racc[r][0][j]; v0 = v0 > 0.f ? v0 : 0.f; racc[r][0][j] = v0 * e.x;
      float v1 = racc[r][1][j]; v1 = v1 > 0.f ? v1 : 0.f; racc[r][1][j] = v1 * e.y;
    }

  // ---- Phase E: in-register segmented column sums (rf-skip); interior store, edge atomic
  unsigned long long mm = bmask;
  while (mm) {
    const int a = __builtin_ctzll(mm);
    mm &= mm - 1;
    const int b = mm ? __builtin_ctzll(mm) : 64;
    const int g = __shfl(gv, a, 64);
    float s0 = 0.f, s1 = 0.f;
    #pragma unroll
    for (int r = 0; r < 4; ++r) {
      if (16 * r + 15 < a || 16 * r >= b) continue;   // wave-uniform rowfrag skip
      #pragma unroll
      for (int j = 0; j < 4; ++j) {
        const int row = 16 * r + 4 * lg + j;
        const float msk = ((unsigned)(row - a) < (unsigned)(b - a)) ? 1.f : 0.f;
        s0 = fmaf(msk, racc[r][0][j], s0);
        s1 = fmaf(msk, racc[r][1][j], s1);
      }
    }
    s0 += __shfl_xor(s0, 16, 64); s0 += __shfl_xor(s0, 32, 64);
    s1 += __shfl_xor(s1, 16, 64); s1 += __shfl_xor(s1, 32, 64);
    const bool edge = (a == 0) || (b == 64);
    if (lane < 16) {
      float* dst = out + (size_t)g * GDIM + 32 * w + lane;
      if (edge) { atomicAdd(dst, s0); atomicAdd(dst + 16, s1); }
      else      { dst[0] = s0; dst[16] = s1; }
    }
  }
}

// ---------------- epilogue: out[g][c] /= denom[g][c/16]; empty graphs -> 0 ----------------
__global__ void k_div(float* __restrict__ out, const float* __restrict__ denom) {
  int i = blockIdx.x * 256 + threadIdx.x;
  if (i >= NG * GDIM / 4) return;
  float d = denom[(size_t)(i >> 6) * NH + ((i & 63) >> 2)];
  float r = d > 0.f ? 1.0f / d : 0.f;
  float4 v = ((float4*)out)[i];
  v.x *= r; v.y *= r; v.z *= r; v.w *= r;
  ((float4*)out)[i] = v;
}

extern "C" void kernel_launch(void* const* d_in, const int* in_sizes, int n_in,
                              void* d_out, int out_size, void* d_ws, size_t ws_size,
                              hipStream_t stream) {
  (void)in_sizes; (void)n_in; (void)out_size; (void)ws_size;
  const float* X  = (const float*)d_in[0];
  const int* seg  = (const int*)d_in[1];
  const float* s1 = (const float*)d_in[3];
  const float* s2 = (const float*)d_in[4];
  const float* t1 = (const float*)d_in[5];
  const float* t2 = (const float*)d_in[6];
  float* out = (float*)d_out;
  char* ws = (char*)d_ws;

  unsigned short* WB = (unsigned short*)ws;
  float* denom = (float*)(ws + (1 << 19));

  k_init<<<NZBLK + 392, 256, 0, stream>>>(s1, s2, t1, t2, WB, out, denom);
  k_main<<<NTILES, 512, 0, stream>>>(X, WB, WB + 32768, WB + 98304, WB + 65536,
                                     seg, denom, out);
  k_div<<<12500, 256, 0, stream>>>(out, denom);
}

// Round 16
// 407.476 us; speedup vs baseline: 1.0211x; 1.0211x over previous
//
#include <hip/hip_runtime.h>
#include <stdint.h>

#define VN   1000000
#define VDIM 256
#define GDIM 256
#define NH   16
#define NG   50000
#define HIDD 128
#define NTILES 15625   // VN / 64
#define NZBLK 13282    // zero blocks: ceil((NG*GDIM/4 + NG*NH/4)/256)

using bf16x8 = __attribute__((ext_vector_type(8))) __bf16;
using f32x4  = __attribute__((ext_vector_type(4))) float;

__device__ __forceinline__ unsigned short f2bf(float f) {
  __bf16 h = (__bf16)f;                 // native RNE (v_cvt_pk_bf16_f32)
  return __builtin_bit_cast(unsigned short, h);
}
__device__ __forceinline__ bf16x8 pack8(float4 a, float4 b) {
  bf16x8 r;
  r[0] = (__bf16)a.x; r[1] = (__bf16)a.y; r[2] = (__bf16)a.z; r[3] = (__bf16)a.w;
  r[4] = (__bf16)b.x; r[5] = (__bf16)b.y; r[6] = (__bf16)b.z; r[7] = (__bf16)b.w;
  return r;
}
__device__ __forceinline__ f32x4 fzero4() { f32x4 z = {0.f, 0.f, 0.f, 0.f}; return z; }

// ---------------- init: zero out+denom AND weight prep (merged, one launch) ----------------
// blocks [0, NZBLK): zero out [NG*GDIM] + denom [NG*NH]
// blocks [NZBLK, NZBLK+392): fp32 -> bf16 MFMA B-fragment reorder
// For W[K][N]: frag element idx = ((c*(K/32)+s)*64 + lane)*8 + j holds W[32s+8*(lane>>4)+j][16c+(lane&15)]
__global__ void k_init(const float* __restrict__ s1, const float* __restrict__ s2,
                       const float* __restrict__ t1, const float* __restrict__ t2,
                       unsigned short* __restrict__ WB,
                       float* __restrict__ out, float* __restrict__ denom) {
  if (blockIdx.x < NZBLK) {
    int i = blockIdx.x * 256 + threadIdx.x;
    float4 z = make_float4(0.f, 0.f, 0.f, 0.f);
    if (i < NG * GDIM / 4) ((float4*)out)[i] = z;
    int j = i - NG * GDIM / 4;
    if (j >= 0 && j < NG * NH / 4) ((float4*)denom)[j] = z;
    return;
  }
  int t = (blockIdx.x - NZBLK) * 256 + threadIdx.x;
  const float* W; unsigned short* dst; int K, N, lid;
  if (t < 32768)       { W = s1; dst = WB;          K = 256; N = 128; lid = t; }
  else if (t < 65536)  { W = t1; dst = WB + 32768;  K = 256; N = 128; lid = t - 32768; }
  else if (t < 98304)  { W = t2; dst = WB + 65536;  K = 128; N = 256; lid = t - 65536; }
  else if (t < 100352) { W = s2; dst = WB + 98304;  K = 128; N = 16;  lid = t - 98304; }
  else return;
  int j = lid & 7, l = (lid >> 3) & 63, rem = lid >> 9;
  int KS = K >> 5;
  int s = rem % KS, c = rem / KS;
  int row = 32 * s + 8 * (l >> 4) + j;
  int col = 16 * c + (l & 15);
  dst[lid] = f2bf(W[row * N + col]);
}

// ---------------- fused main: one 64-row tile per block, 512 thr / 8 waves ----------------
// LDS (68 KB): Xs [0,32768); Hs [32768,49152); Ts [49152,65536); exs f32[64][16] [65536,69632)
// Best measured config (R14, 407.8 us total): lb(512,2) -> VGPR cap 128 (several-ks-deep
// weight-fragment hoisting, no spill), 2 blocks/CU x 8 waves = 16 waves/CU, 3 barriers/tile,
// 8 waves x 2 col-frags (minimal per-wave weight streams), nothing held across barriers.
// Occupancy sweep closed: cap64/4blk=496us, cap85/3blk=416us, cap128/2blk=408us.
__global__ __launch_bounds__(512, 2) void k_main(
    const float* __restrict__ X,
    const unsigned short* __restrict__ WBs1,
    const unsigned short* __restrict__ WBt1,
    const unsigned short* __restrict__ WBs2,
    const unsigned short* __restrict__ WBt2,
    const int* __restrict__ seg,
    float* __restrict__ denom,
    float* __restrict__ out) {
  __shared__ __align__(16) char U[69632];
  char* const Xs = U;
  char* const Hs = U + 32768;
  char* const Ts = U + 49152;
  float* const exs = (float*)(U + 65536);

  const int tid  = threadIdx.x;
  const int lane = tid & 63;
  const int w    = tid >> 6;     // 0..7
  const int lg   = lane >> 4;
  const int ml   = lane & 15;
  const size_t base = (size_t)blockIdx.x * 64;

  // per-lane graph id for the tile's 64 rows (lane <-> row)
  const int gv = seg[base + lane];
  const int gp = __shfl_up(gv, 1, 64);
  const unsigned long long bmask = __ballot(gv != gp) | 1ull;  // segment-start rows

  // ---- Phase A: stage X -> bf16 LDS. 32B chunks: 2x float4 -> pack8 (cvt_pk) -> one 16B swz write
  {
    const float4* Xg = (const float4*)(X + base * VDIM);
    #pragma unroll
    for (int p = 0; p < 4; ++p) {
      const int c32 = tid + 512 * p;          // 32B fp32 chunk, 2048 total
      const int row = c32 >> 5, c8 = c32 & 31;
      float4 a = Xg[2 * c32], b = Xg[2 * c32 + 1];
      *(bf16x8*)(Xs + row * 512 + ((c8 * 16) ^ ((row & 7) << 4))) = pack8(a, b);
    }
  }
  __syncthreads();   // bar1: Xs ready

  // ---- Phase B: C1[64][256] = relu(X @ [Sw1|Tw1]); waves 0-3 -> Sw1 cf{2w,2w+1}, 4-7 -> Tw1
  const unsigned short* Wb1 = (w < 4) ? WBs1 : WBt1;
  const int cw = 2 * (w & 3);
  {
    f32x4 acc[4][2];
    #pragma unroll
    for (int r = 0; r < 4; ++r) { acc[r][0] = fzero4(); acc[r][1] = fzero4(); }

    #pragma unroll
    for (int ks = 0; ks < 8; ++ks) {
      bf16x8 A[4];
      #pragma unroll
      for (int r = 0; r < 4; ++r) {
        const int row = 16 * r + ml;
        const int cb = 64 * ks + 16 * lg;
        A[r] = *(const bf16x8*)(Xs + row * 512 + (cb ^ ((row & 7) << 4)));
      }
      #pragma unroll
      for (int ci = 0; ci < 2; ++ci) {
        bf16x8 B = *(const bf16x8*)(Wb1 + (size_t)(((cw + ci) * 8 + ks) * 64 + lane) * 8);
        #pragma unroll
        for (int r = 0; r < 4; ++r)
          acc[r][ci] = __builtin_amdgcn_mfma_f32_16x16x32_bf16(A[r], B, acc[r][ci], 0, 0, 0);
      }
    }
    // relu + bf16 -> Hs (waves 0-3) / Ts (waves 4-7): separate buffers, NO barrier needed
    char* const dst = (w < 4) ? Hs : Ts;
    #pragma unroll
    for (int ci = 0; ci < 2; ++ci) {
      const int colf = cw + ci;
      #pragma unroll
      for (int r = 0; r < 4; ++r)
        #pragma unroll
        for (int j = 0; j < 4; ++j) {
          const int row = 16 * r + 4 * lg + j;
          const int col = 16 * colf + ml;
          float v = acc[r][ci][j];
          v = v > 0.f ? v : 0.f;
          *(unsigned short*)(dst + row * 256 + ((col * 2) ^ ((row & 7) << 4))) = f2bf(v);
        }
    }
  }
  __syncthreads();   // bar2: Hs/Ts complete

  // ---- Phase C1 (waves 0-3): scores = H1 @ Sw2, rows 16w..16w+15; ex -> exs + denom atomics
  if (w < 4) {
    f32x4 sa = fzero4();
    #pragma unroll
    for (int ks = 0; ks < 4; ++ks) {
      const int row = 16 * w + ml;
      const int cb = 64 * ks + 16 * lg;
      bf16x8 A2 = *(const bf16x8*)(Hs + row * 256 + (cb ^ ((row & 7) << 4)));
      bf16x8 B2 = *(const bf16x8*)(WBs2 + (size_t)(ks * 64 + lane) * 8);
      sa = __builtin_amdgcn_mfma_f32_16x16x32_bf16(A2, B2, sa, 0, 0, 0);
    }
    const int rowbase = 16 * w + 4 * lg;
    float ex[4]; int gs[4];
    #pragma unroll
    for (int j = 0; j < 4; ++j) {
      ex[j] = __expf(sa[j]);                     // |score| ~< 1.5: no max-subtract needed
      gs[j] = __shfl(gv, rowbase + j, 64);
      exs[(rowbase + j) * 16 + ml] = ex[j];
    }
    float accd = ex[0]; int gcur = gs[0];
    #pragma unroll
    for (int j = 1; j < 4; ++j) {
      if (gs[j] == gcur) accd += ex[j];
      else { atomicAdd(denom + (size_t)gcur * NH + ml, accd); gcur = gs[j]; accd = ex[j]; }
    }
    atomicAdd(denom + (size_t)gcur * NH + ml, accd);
  }

  // ---- Phase C2: R = T1 @ Tw2 ; wave w -> col-frags {2w, 2w+1} of 16
  f32x4 racc[4][2];
  #pragma unroll
  for (int r = 0; r < 4; ++r) { racc[r][0] = fzero4(); racc[r][1] = fzero4(); }
  #pragma unroll
  for (int ks = 0; ks < 4; ++ks) {
    bf16x8 A[4];
    #pragma unroll
    for (int r = 0; r < 4; ++r) {
      const int row = 16 * r + ml;
      const int cb = 64 * ks + 16 * lg;
      A[r] = *(const bf16x8*)(Ts + row * 256 + (cb ^ ((row & 7) << 4)));
    }
    #pragma unroll
    for (int ci = 0; ci < 2; ++ci) {
      bf16x8 B = *(const bf16x8*)(WBt2 + (size_t)(((2 * w + ci) * 4 + ks) * 64 + lane) * 8);
      #pragma unroll
      for (int r = 0; r < 4; ++r)
        racc[r][ci] = __builtin_amdgcn_mfma_f32_16x16x32_bf16(A[r], B, racc[r][ci], 0, 0, 0);
    }
  }
  __syncthreads();   // bar3: exs fully written by all C1 waves

  // ---- Phase D: racc = relu(racc) * ex[row][2w+ci]
  #pragma unroll
  for (int r = 0; r < 4; ++r)
    #pragma unroll
    for (int j = 0; j < 4; ++j) {
      const int row = 16 * r + 4 * lg + j;
      const float2 e = *(const float2*)(exs + row * 16 + 2 * w);
      float v0 = racc[r][0][j]; v0 = v0 > 0.f ? v0 : 0.f; racc[r][0][j] = v0 * e.x;
      float v1 = racc[r][1][j]; v1 = v1 > 0.f ? v1 : 0.f; racc[r][1][j] = v1 * e.y;
    }

  // ---- Phase E: in-register segmented column sums (rf-skip); interior store, edge atomic
  unsigned long long mm = bmask;
  while (mm) {
    const int a = __builtin_ctzll(mm);
    mm &= mm - 1;
    const int b = mm ? __builtin_ctzll(mm) : 64;
    const int g = __shfl(gv, a, 64);
    float s0 = 0.f, s1 = 0.f;
    #pragma unroll
    for (int r = 0; r < 4; ++r) {
      if (16 * r + 15 < a || 16 * r >= b) continue;   // wave-uniform rowfrag skip
      #pragma unroll
      for (int j = 0; j < 4; ++j) {
        const int row = 16 * r + 4 * lg + j;
        const float msk = ((unsigned)(row - a) < (unsigned)(b - a)) ? 1.f : 0.f;
        s0 = fmaf(msk, racc[r][0][j], s0);
        s1 = fmaf(msk, racc[r][1][j], s1);
      }
    }
    s0 += __shfl_xor(s0, 16, 64); s0 += __shfl_xor(s0, 32, 64);
    s1 += __shfl_xor(s1, 16, 64); s1 += __shfl_xor(s1, 32, 64);
    const bool edge = (a == 0) || (b == 64);
    if (lane < 16) {
      float* dst = out + (size_t)g * GDIM + 32 * w + lane;
      if (edge) { atomicAdd(dst, s0); atomicAdd(dst + 16, s1); }
      else      { dst[0] = s0; dst[16] = s1; }
    }
  }
}

// ---------------- epilogue: out[g][c] /= denom[g][c/16]; empty graphs -> 0 ----------------
__global__ void k_div(float* __restrict__ out, const float* __restrict__ denom) {
  int i = blockIdx.x * 256 + threadIdx.x;
  if (i >= NG * GDIM / 4) return;
  float d = denom[(size_t)(i >> 6) * NH + ((i & 63) >> 2)];
  float r = d > 0.f ? 1.0f / d : 0.f;
  float4 v = ((float4*)out)[i];
  v.x *= r; v.y *= r; v.z *= r; v.w *= r;
  ((float4*)out)[i] = v;
}

extern "C" void kernel_launch(void* const* d_in, const int* in_sizes, int n_in,
                              void* d_out, int out_size, void* d_ws, size_t ws_size,
                              hipStream_t stream) {
  (void)in_sizes; (void)n_in; (void)out_size; (void)ws_size;
  const float* X  = (const float*)d_in[0];
  const int* seg  = (const int*)d_in[1];
  const float* s1 = (const float*)d_in[3];
  const float* s2 = (const float*)d_in[4];
  const float* t1 = (const float*)d_in[5];
  const float* t2 = (const float*)d_in[6];
  float* out = (float*)d_out;
  char* ws = (char*)d_ws;

  unsigned short* WB = (unsigned short*)ws;
  float* denom = (float*)(ws + (1 << 19));

  k_init<<<NZBLK + 392, 256, 0, stream>>>(s1, s2, t1, t2, WB, out, denom);
  k_main<<<NTILES, 512, 0, stream>>>(X, WB, WB + 32768, WB + 98304, WB + 65536,
                                     seg, denom, out);
  k_div<<<12500, 256, 0, stream>>>(out, denom);
}